// Round 1
// baseline (154.625 us; speedup 1.0000x reference)
//
#include <hip/hip_runtime.h>

// BasisFunction2D: out[o,b] = sum_{i,j,ci,cj} wx*wz * P[gx+ci, gz+cj, o, i, j]
// Strategy: one block per (o,i) pair (2048 blocks). Stage the 17*17*32-float
// slice P[:,:,o,i,:] (37 KB) into LDS once (P read from HBM exactly once,
// 76 MB total), then all 512 batch elements gather from LDS.
// Reduction over i via atomicAdd into out (zeroed by hipMemsetAsync).

#define NG        16
#define NB        17          // NG+1
#define IN_X      32
#define IN_Z      32
#define OUT_DIM   64
#define BATCH     512
#define CELLS     (NB * NB)   // 289
#define LDS_STR   33          // 32 + 1 pad -> bank = (cell + j) % 32

__device__ __forceinline__ void grid_coord(float v,
                                           const float* __restrict__ borders,
                                           const float* __restrict__ inv_len,
                                           int& idx, float& w) {
    float e   = expf(-fabsf(v));
    float cdf = (v > 0.f) ? (1.f - 0.5f * e) : (0.5f * e);
    int t = (int)(cdf * 16.f);
    t = t < 0 ? 0 : (t > NG - 1 ? NG - 1 : t);
    idx = t;
    w = (v - borders[t]) * inv_len[t];
}

__global__ void bf2d_kernel(const float* __restrict__ x,
                            const float* __restrict__ z,
                            const float* __restrict__ P,
                            const float* __restrict__ borders,
                            const float* __restrict__ inv_len,
                            float* __restrict__ out) {
    __shared__ float lds[CELLS * LDS_STR];   // 9537 floats = 38148 B

    const int tid = threadIdx.x;             // 256 threads
    const int o   = blockIdx.x & (OUT_DIM - 1);
    const int i   = blockIdx.x >> 6;

    // ---- stage P[:, :, o, i, :] into LDS (coalesced 128B rows per cell) ----
    const float* Pbase = P + ((size_t)o * (IN_X * IN_Z) + (size_t)i * IN_Z);
    for (int k = tid; k < CELLS * IN_Z; k += 256) {
        const int c = k >> 5;                // cell = gx*17 + gz
        const int j = k & 31;
        lds[c * LDS_STR + j] = Pbase[(size_t)c * (OUT_DIM * IN_X * IN_Z) + j];
    }
    __syncthreads();

    // ---- per-thread: 2 batch elements ----
    float acc0 = 0.f, acc1 = 0.f;
    int   gx0, gx1;
    float wx0, wx1;
    {
        float vx0 = x[i * BATCH + tid];
        float vx1 = x[i * BATCH + tid + 256];
        grid_coord(vx0, borders, inv_len, gx0, wx0);
        grid_coord(vx1, borders, inv_len, gx1, wx1);
    }
    const int cx0 = gx0 * NB;   // row offset in cell space
    const int cx1 = gx1 * NB;

    for (int j = 0; j < IN_Z; ++j) {
        // batch element tid
        {
            float vz = z[j * BATCH + tid];
            int gz; float wz;
            grid_coord(vz, borders, inv_len, gz, wz);
            const float* p = &lds[(cx0 + gz) * LDS_STR + j];
            float v00 = p[0];
            float v01 = p[LDS_STR];
            float v10 = p[NB * LDS_STR];
            float v11 = p[(NB + 1) * LDS_STR];
            float lo = v00 + wz * (v01 - v00);
            float hi = v10 + wz * (v11 - v10);
            acc0 += lo + wx0 * (hi - lo);
        }
        // batch element tid + 256
        {
            float vz = z[j * BATCH + tid + 256];
            int gz; float wz;
            grid_coord(vz, borders, inv_len, gz, wz);
            const float* p = &lds[(cx1 + gz) * LDS_STR + j];
            float v00 = p[0];
            float v01 = p[LDS_STR];
            float v10 = p[NB * LDS_STR];
            float v11 = p[(NB + 1) * LDS_STR];
            float lo = v00 + wz * (v01 - v00);
            float hi = v10 + wz * (v11 - v10);
            acc1 += lo + wx1 * (hi - lo);
        }
    }

    atomicAdd(&out[o * BATCH + tid],        acc0);
    atomicAdd(&out[o * BATCH + tid + 256],  acc1);
}

extern "C" void kernel_launch(void* const* d_in, const int* in_sizes, int n_in,
                              void* d_out, int out_size, void* d_ws, size_t ws_size,
                              hipStream_t stream) {
    const float* x       = (const float*)d_in[0];   // (32, 512)
    const float* z       = (const float*)d_in[1];   // (32, 512)
    const float* P       = (const float*)d_in[2];   // (17,17,64,32,32)
    const float* borders = (const float*)d_in[3];   // (17,)
    const float* inv_len = (const float*)d_in[4];   // (16,)
    float* out = (float*)d_out;                     // (64, 512)

    hipMemsetAsync(out, 0, (size_t)out_size * sizeof(float), stream);

    dim3 grid(OUT_DIM * IN_X);   // 2048 blocks: (o, i)
    dim3 block(256);
    bf2d_kernel<<<grid, block, 0, stream>>>(x, z, P, borders, inv_len, out);
}

// Round 2
// 133.633 us; speedup vs baseline: 1.1571x; 1.1571x over previous
//
#include <hip/hip_runtime.h>

// BasisFunction2D, round 2.
// Kernel 1 (precompute): per x/z value, compute grid index + bilinear weight
//   once (reference recomputed these 2048x per value inside the hot loop),
//   store as float2{w, as_float(lds_element_offset)} in d_ws; also zero out.
// Kernel 2 (main): one block per (o,i), 512 threads = 1 batch element each.
//   Stage P[:,:,o,i,:] (37 KB) into LDS (P read from HBM/L3 exactly once),
//   gather 4 corners per (j,b) via ds_read2_b32 pairs, accumulate over j,
//   atomicAdd over i into out.

#define NG        16
#define NB        17            // NG+1
#define IN_X      32
#define IN_Z      32
#define OUT_DIM   64
#define BATCH     512
#define CELLS     (NB * NB)     // 289
#define LDS_STR   33            // 32 + 1 pad: bank = (cell + j) % 32
#define XSTR      (NB * LDS_STR) // 561 elements per gx step

__device__ __forceinline__ void grid_coord(float v,
                                           const float* __restrict__ borders,
                                           const float* __restrict__ inv_len,
                                           int& idx, float& w) {
    float e   = expf(-fabsf(v));
    float cdf = (v > 0.f) ? (1.f - 0.5f * e) : (0.5f * e);
    int t = (int)(cdf * 16.f);
    t = t < 0 ? 0 : (t > NG - 1 ? NG - 1 : t);
    idx = t;
    w = (v - borders[t]) * inv_len[t];
}

// 32768 threads: gid<16384 -> x table, else z table. Also zeroes out[] (32768 el).
__global__ void precompute_kernel(const float* __restrict__ x,
                                  const float* __restrict__ z,
                                  const float* __restrict__ borders,
                                  const float* __restrict__ inv_len,
                                  float2* __restrict__ xc,   // [32*512]
                                  float2* __restrict__ zc,   // [32*512]
                                  float* __restrict__ out) {
    const int gid = blockIdx.x * blockDim.x + threadIdx.x;
    out[gid] = 0.f;
    int idx; float w;
    if (gid < IN_X * BATCH) {
        grid_coord(x[gid], borders, inv_len, idx, w);
        xc[gid] = make_float2(w, __int_as_float(idx * XSTR));
    } else {
        const int g = gid - IN_X * BATCH;
        grid_coord(z[g], borders, inv_len, idx, w);
        zc[g] = make_float2(w, __int_as_float(idx * LDS_STR));
    }
}

__global__ __launch_bounds__(512, 8)
void bf2d_kernel(const float2* __restrict__ xc,
                 const float2* __restrict__ zc,
                 const float* __restrict__ P,
                 float* __restrict__ out) {
    __shared__ float lds[CELLS * LDS_STR];   // 9537 floats = 38148 B

    const int tid = threadIdx.x;             // 512 threads = batch element
    const int o   = blockIdx.x & (OUT_DIM - 1);
    const int i   = blockIdx.x >> 6;

    // ---- stage P[:, :, o, i, :] into LDS ----
    const float* Pbase = P + ((size_t)o * (IN_X * IN_Z) + (size_t)i * IN_Z);
    for (int k = tid; k < CELLS * IN_Z; k += 512) {
        const int c = k >> 5;                // cell = gx*17 + gz
        const int j = k & 31;
        lds[c * LDS_STR + j] = Pbase[(size_t)c * (OUT_DIM * IN_X * IN_Z) + j];
    }
    __syncthreads();

    // ---- per-thread: 1 batch element ----
    const float2 xcv = xc[i * BATCH + tid];
    const float  wx  = xcv.x;
    const int    xoff = __float_as_int(xcv.y);

    float acc = 0.f;
    #pragma unroll 4
    for (int j = 0; j < IN_Z; ++j) {
        const float2 zcv = zc[j * BATCH + tid];       // L2-resident table
        const float  wz  = zcv.x;
        const int    base = xoff + __float_as_int(zcv.y);
        const float* p = &lds[base + j];
        const float  v00 = p[0];
        const float  v01 = p[LDS_STR];                // ds_read2_b32 pair
        const float* q = p + XSTR;
        const float  v10 = q[0];
        const float  v11 = q[LDS_STR];                // ds_read2_b32 pair
        const float  lo = v00 + wz * (v01 - v00);
        const float  hi = v10 + wz * (v11 - v10);
        acc += lo + wx * (hi - lo);
    }

    atomicAdd(&out[o * BATCH + tid], acc);
}

extern "C" void kernel_launch(void* const* d_in, const int* in_sizes, int n_in,
                              void* d_out, int out_size, void* d_ws, size_t ws_size,
                              hipStream_t stream) {
    const float* x       = (const float*)d_in[0];   // (32, 512)
    const float* z       = (const float*)d_in[1];   // (32, 512)
    const float* P       = (const float*)d_in[2];   // (17,17,64,32,32)
    const float* borders = (const float*)d_in[3];   // (17,)
    const float* inv_len = (const float*)d_in[4];   // (16,)
    float* out = (float*)d_out;                     // (64, 512) = 32768

    float2* xc = (float2*)d_ws;                     // 16384 float2 = 128 KB
    float2* zc = xc + IN_X * BATCH;                 // 16384 float2 = 128 KB

    precompute_kernel<<<dim3(128), dim3(256), 0, stream>>>(
        x, z, borders, inv_len, xc, zc, out);

    bf2d_kernel<<<dim3(OUT_DIM * IN_X), dim3(512), 0, stream>>>(xc, zc, P, out);
}

// Round 3
// 131.083 us; speedup vs baseline: 1.1796x; 1.0195x over previous
//
#include <hip/hip_runtime.h>

// BasisFunction2D, round 3.
// Kernel 1 (precompute): per x/z value compute grid index + weight once,
//   store float2{w, as_float(lds_element_offset)}; also zeroes out.
// Kernel 2 (main): one block per (o-pair, i) -> 1024 blocks, 512 threads
//   = 1 batch element each. Stage P[:,:,{o0,o1},i,:] interleaved as float2
//   (76.3 KB LDS, 2 blocks/CU). Each corner gather is one ds_read2_b64
//   serving both outputs -> half the LDS instrs, half the zc traffic,
//   2x ILP vs round 2. atomicAdd over i into out.

#define NG        16
#define NB        17             // NG+1
#define IN_X      32
#define IN_Z      32
#define OUT_DIM   64
#define BATCH     512
#define CELLS     (NB * NB)      // 289
#define LDS_STR   33             // 32 + 1 pad (element units)
#define XSTR      (NB * LDS_STR) // 561 elements per gx step

__device__ __forceinline__ void grid_coord(float v,
                                           const float* __restrict__ borders,
                                           const float* __restrict__ inv_len,
                                           int& idx, float& w) {
    float e   = expf(-fabsf(v));
    float cdf = (v > 0.f) ? (1.f - 0.5f * e) : (0.5f * e);
    int t = (int)(cdf * 16.f);
    t = t < 0 ? 0 : (t > NG - 1 ? NG - 1 : t);
    idx = t;
    w = (v - borders[t]) * inv_len[t];
}

// 32768 threads: gid<16384 -> x table, else z table. Also zeroes out[] (32768).
__global__ void precompute_kernel(const float* __restrict__ x,
                                  const float* __restrict__ z,
                                  const float* __restrict__ borders,
                                  const float* __restrict__ inv_len,
                                  float2* __restrict__ xc,   // [32*512]
                                  float2* __restrict__ zc,   // [32*512]
                                  float* __restrict__ out) {
    const int gid = blockIdx.x * blockDim.x + threadIdx.x;
    out[gid] = 0.f;
    int idx; float w;
    if (gid < IN_X * BATCH) {
        grid_coord(x[gid], borders, inv_len, idx, w);
        xc[gid] = make_float2(w, __int_as_float(idx * XSTR));
    } else {
        const int g = gid - IN_X * BATCH;
        grid_coord(z[g], borders, inv_len, idx, w);
        zc[g] = make_float2(w, __int_as_float(idx * LDS_STR));
    }
}

__global__ __launch_bounds__(512, 4)
void bf2d_kernel(const float2* __restrict__ xc,
                 const float2* __restrict__ zc,
                 const float* __restrict__ P,
                 float* __restrict__ out) {
    // lds2[e] = (P[cell,o0,i,j], P[cell,o1,i,j]) with e = cell*33 + j
    __shared__ float2 lds2[CELLS * LDS_STR];   // 9537 * 8 B = 76296 B

    const int tid = threadIdx.x;               // 512 threads = batch element
    const int o0  = (blockIdx.x & 31) * 2;     // o-pair
    const int i   = blockIdx.x >> 5;

    // ---- stage P[:, :, {o0,o0+1}, i, :] into LDS as float2 ----
    const float* Pbase = P + ((size_t)o0 * (IN_X * IN_Z) + (size_t)i * IN_Z);
    for (int k = tid; k < CELLS * IN_Z; k += 512) {
        const int c = k >> 5;                  // cell = gx*17 + gz
        const int j = k & 31;
        const size_t g = (size_t)c * (OUT_DIM * IN_X * IN_Z) + j;
        lds2[c * LDS_STR + j] = make_float2(Pbase[g], Pbase[g + IN_X * IN_Z]);
    }
    __syncthreads();

    // ---- per-thread: 1 batch element, 2 outputs ----
    const float2 xcv  = xc[i * BATCH + tid];
    const float  wx   = xcv.x;
    const int    xoff = __float_as_int(xcv.y);

    const float2* zp = zc + tid;
    float accx = 0.f, accy = 0.f;
    #pragma unroll 4
    for (int j = 0; j < IN_Z; ++j) {
        const float2 zcv = zp[j * BATCH];           // L2-resident table
        const float  wz  = zcv.x;
        const int    base = xoff + __float_as_int(zcv.y) + j;
        const float2 a0 = lds2[base];               // (cx  , cz  ) both o
        const float2 a1 = lds2[base + LDS_STR];     // (cx  , cz+1)  -> ds_read2_b64
        const float2 b0 = lds2[base + XSTR];        // (cx+1, cz  )
        const float2 b1 = lds2[base + XSTR + LDS_STR]; //              -> ds_read2_b64
        const float lox = a0.x + wz * (a1.x - a0.x);
        const float loy = a0.y + wz * (a1.y - a0.y);
        const float hix = b0.x + wz * (b1.x - b0.x);
        const float hiy = b0.y + wz * (b1.y - b0.y);
        accx += lox + wx * (hix - lox);
        accy += loy + wx * (hiy - loy);
    }

    atomicAdd(&out[o0 * BATCH + tid],       accx);
    atomicAdd(&out[(o0 + 1) * BATCH + tid], accy);
}

extern "C" void kernel_launch(void* const* d_in, const int* in_sizes, int n_in,
                              void* d_out, int out_size, void* d_ws, size_t ws_size,
                              hipStream_t stream) {
    const float* x       = (const float*)d_in[0];   // (32, 512)
    const float* z       = (const float*)d_in[1];   // (32, 512)
    const float* P       = (const float*)d_in[2];   // (17,17,64,32,32)
    const float* borders = (const float*)d_in[3];   // (17,)
    const float* inv_len = (const float*)d_in[4];   // (16,)
    float* out = (float*)d_out;                     // (64, 512) = 32768

    float2* xc = (float2*)d_ws;                     // 16384 float2
    float2* zc = xc + IN_X * BATCH;                 // 16384 float2

    precompute_kernel<<<dim3(128), dim3(256), 0, stream>>>(
        x, z, borders, inv_len, xc, zc, out);

    bf2d_kernel<<<dim3((OUT_DIM / 2) * IN_X), dim3(512), 0, stream>>>(
        xc, zc, P, out);
}